// Round 18
// baseline (74.796 us; speedup 1.0000x reference)
//
#include <hip/hip_runtime.h>
#include <hip/hip_bf16.h>

typedef float    f32x2  __attribute__((ext_vector_type(2)));
typedef float    f32x4  __attribute__((ext_vector_type(4)));
typedef float    f32x16 __attribute__((ext_vector_type(16)));
typedef _Float16 f16x8  __attribute__((ext_vector_type(8)));
typedef _Float16 f16x4  __attribute__((ext_vector_type(4)));
typedef _Float16 f16x2  __attribute__((ext_vector_type(2)));

#define VP 264   // vlds co-pitch: rows 16B-aligned, 33x16B units ≡ 1 mod 8 -> b128-clean
#define XP 132   // xs plane-pitch: lane stride 66 words ≡ 2 mod 32 -> 2-way (free)
#define AP 264   // act16 pitch
#define RP 36    // route16 pitch (72B rows, b64-aligned)

// ---------------------------------------------------------------------------
// Kernel 0: W [144][256] f32 -> wt [co(256)][tap(9)][kd(16)] fp16
// ---------------------------------------------------------------------------
__global__ __launch_bounds__(256) void prep_wt_kernel(
    const float* __restrict__ W, _Float16* __restrict__ wt)
{
    const int k = blockIdx.x;      // 0..143 ; kd = k/9, tap = k%9
    const int t = threadIdx.x;     // co
    wt[t * 144 + (k % 9) * 16 + (k / 9)] = (_Float16)W[k * 256 + t];
}

// ---------------------------------------------------------------------------
// Fused kernel: block = XCD-swizzled (b,h), 1024 threads / 16 waves.
// Conv: wave = (co-tile, d-half) -> votes in vlds.
// Phase B: thread = (oa-pair, w-group-of-4): f16x2 votes, f16x4 route.
// Phase A/C: 960 threads = (i, w, o-quad); logits as lreg4[4] in registers;
//            softmax combine via 2-stage shfl_xor within the 4-lane o-quad.
// ---------------------------------------------------------------------------
__global__ __launch_bounds__(1024, 4) void fused_kernel(
    const float* __restrict__ x, const _Float16* __restrict__ wt,
    const float* __restrict__ bias, float* __restrict__ out)
{
    // XCD swizzle: 960 blocks = 8 XCDs x 120
    const int bid = blockIdx.x;
    const int wid = (bid & 7) * 120 + (bid >> 3);
    const int b = wid / 30, h = wid - 30 * b;
    const int t = threadIdx.x;  // 0..1023

    __shared__ alignas(16) _Float16 vlds[8 * 30 * VP];   // 126,720 B
    __shared__ alignas(16) union {
        _Float16 xs[3][36][XP];                     // 28,512 B (conv phase)
        struct {                                    // routing phase
            _Float16 route16[8 * 16 * RP];          //  9,216 B
            _Float16 act16[30 * AP];                // 15,840 B
            f32x2    s2buf[8][128];                 //  8,192 B
        } rt;
    } u;                                            // total 159,968 B

    // ---- stage x: plane-pair packed writes
    {
        const float* xb = x + (size_t)b * 131072;
        f32x4 v0[2], v1[2];
        int p0s[2], rs[2], c4s[2];
        #pragma unroll
        for (int j = 0; j < 2; ++j) {
            int q = t + j * 1024;
            bool ok = q < 1536;
            int qq = ok ? q : 0;
            int g  = qq / 24;
            p0s[j] = g * 2;
            int rem = qq - g * 24;
            rs[j] = rem >> 3; c4s[j] = rem & 7;
            if (ok) {
                v0[j] = *(const f32x4*)(xb + p0s[j] * 1024 + (h + rs[j]) * 32 + c4s[j] * 4);
                v1[j] = *(const f32x4*)(xb + (p0s[j] + 1) * 1024 + (h + rs[j]) * 32 + c4s[j] * 4);
            }
        }
        if (t < 768) {      // zero-fill cols 32..35 (plane pairs)
            int r = t / 256, rem = t - r * 256;
            int c = rem >> 6, pz = (rem & 63) * 2;
            *(f16x2*)&u.xs[r][32 + c][pz] = f16x2{(_Float16)0.f, (_Float16)0.f};
        }
        #pragma unroll
        for (int j = 0; j < 2; ++j) {
            if (t + j * 1024 < 1536) {
                #pragma unroll
                for (int c = 0; c < 4; ++c)
                    *(f16x2*)&u.xs[rs[j]][c4s[j] * 4 + c][p0s[j]] =
                        f16x2{(_Float16)v0[j][c], (_Float16)v1[j][c]};
            }
        }
    }
    __syncthreads();

    const int lane = t & 63, wv = t >> 6;   // wv 0..15
    const int l31  = lane & 31;
    const int kb   = lane >> 5;
    const int ct   = wv >> 1, dh = wv & 1;  // co-tile 0..7, d-half 0..1
    const int oaC  = ct * 32 + l31;

    // ---- conv: wave = (ct, dh): 4 d's x 9 K-steps; votes -> vlds
    {
        f16x8 bf[9];
        const _Float16* wp = wt + (size_t)oaC * 144 + kb * 8;
        #pragma unroll
        for (int s = 0; s < 9; ++s) bf[s] = *(const f16x8*)(wp + s * 16);

        #pragma unroll
        for (int dd = 0; dd < 4; ++dd) {
            f32x16 acc = {};
            #pragma unroll
            for (int s = 0; s < 9; ++s) {
                const int kh = s / 3, kw = s - 3 * (s / 3);
                const _Float16* ap = &u.xs[kh][l31 + kw][dh * 64 + dd * 16 + kb * 8];
                f16x4 lo = *(const f16x4*)(ap);
                f16x4 hi = *(const f16x4*)(ap + 4);
                f16x8 af = __builtin_shufflevector(lo, hi, 0, 1, 2, 3, 4, 5, 6, 7);
                acc = __builtin_amdgcn_mfma_f32_32x32x16_f16(af, bf[s], acc, 0, 0, 0);
            }
            const int d = dh * 4 + dd;
            #pragma unroll
            for (int r = 0; r < 16; ++r) {
                const int wr = (r & 3) + 8 * (r >> 2) + 4 * kb;
                if (wr < 30) vlds[(d * 30 + wr) * VP + oaC] = (_Float16)acc[r];
            }
        }
    }
    __syncthreads();

    // ---- routing mappings
    const int oa2 = t & 127;                // phase B: oa pair = 2*oa2, 2*oa2+1
    const int wq8 = t >> 7;                 // w-group 0..7
    const int wbase = wq8 * 4;
    const int o = oa2 >> 3;
    const float biasA = bias[2 * oa2], biasB = bias[2 * oa2 + 1];
    bool wok[4];
    #pragma unroll
    for (int w = 0; w < 4; ++w) wok[w] = (wbase + w) < 30;

    // phase A/C mapping: t < 960 -> (i, w, o-quad)
    const bool acOK = (t < 960);
    const int iC   = t / 120;
    const int remC = t - iC * 120;
    const int wC   = remC >> 2;             // 0..29
    const int oqC  = remC & 3;              // o-quad: owns oo = oqC*4 .. +3

    float lreg4[4];                         // logits[iC][oqC*4+j][wC]
    float preA[4], preB[4];
    float scaleA = 0.f, scaleB = 0.f;

    for (int it = 0; it < 3; ++it) {
        // ---- Phase A (it>0): softmax over o via o-quad shfl; threads t<960
        if (it > 0) {
            if (acOK) {
                float m = fmaxf(fmaxf(lreg4[0], lreg4[1]), fmaxf(lreg4[2], lreg4[3]));
                m = fmaxf(m, __shfl_xor(m, 1));
                m = fmaxf(m, __shfl_xor(m, 2));
                float e[4], ssum = 0.f;
                #pragma unroll
                for (int jj = 0; jj < 4; ++jj) { e[jj] = __expf(lreg4[jj] - m); ssum += e[jj]; }
                ssum += __shfl_xor(ssum, 1);
                ssum += __shfl_xor(ssum, 2);
                float inv = 1.f / ssum;
                #pragma unroll
                for (int jj = 0; jj < 4; ++jj)
                    u.rt.route16[(iC * 16 + oqC * 4 + jj) * RP + wC] = (_Float16)(e[jj] * inv);
            }
            __syncthreads();
        }

        // ---- Phase B: thread (oa2, wq8): pre over 4 w's for 2 oa's
        #pragma unroll
        for (int w = 0; w < 4; ++w) { preA[w] = biasA; preB[w] = biasB; }
        #pragma unroll
        for (int i = 0; i < 8; ++i) {
            f16x2 vv[4];
            #pragma unroll
            for (int w = 0; w < 4; ++w)
                vv[w] = wok[w] ? *(const f16x2*)&vlds[(i * 30 + wbase + w) * VP + 2 * oa2]
                               : f16x2{(_Float16)0.f, (_Float16)0.f};
            if (it == 0) {
                #pragma unroll
                for (int w = 0; w < 4; ++w) {
                    preA[w] = fmaf(0.0625f, (float)vv[w][0], preA[w]);
                    preB[w] = fmaf(0.0625f, (float)vv[w][1], preB[w]);
                }
            } else {
                f16x4 r4 = *(const f16x4*)&u.rt.route16[(i * 16 + o) * RP + wbase];
                #pragma unroll
                for (int w = 0; w < 4; ++w) {
                    float rw = (float)r4[w];
                    preA[w] = fmaf(rw, (float)vv[w][0], preA[w]);
                    preB[w] = fmaf(rw, (float)vv[w][1], preB[w]);
                }
            }
        }
        float s2A = 0.f, s2B = 0.f;
        #pragma unroll
        for (int w = 0; w < 4; ++w) {
            if (wok[w]) {
                s2A = fmaf(preA[w], preA[w], s2A);
                s2B = fmaf(preB[w], preB[w], s2B);
            }
        }
        u.rt.s2buf[wq8][oa2] = f32x2{s2A, s2B};
        __syncthreads();
        float sA = 0.f, sB = 0.f;
        #pragma unroll
        for (int k = 0; k < 8; ++k) {
            f32x2 p = u.rt.s2buf[k][oa2];
            sA += p[0]; sB += p[1];
        }
        scaleA = sA / ((1.f + sA) * sqrtf(sA + 1e-7f));
        scaleB = sB / ((1.f + sB) * sqrtf(sB + 1e-7f));

        if (it < 2) {
            #pragma unroll
            for (int w = 0; w < 4; ++w)
                if (wok[w])
                    *(f16x2*)&u.rt.act16[(wbase + w) * AP + 2 * oa2] =
                        f16x2{(_Float16)(scaleA * preA[w]), (_Float16)(scaleB * preB[w])};
            __syncthreads();
            // ---- Phase C: thread (i,w,oq) t<960: lreg4[j] (+)= sum_a v*act
            if (acOK) {
                const _Float16* vrow = &vlds[(iC * 30 + wC) * VP + oqC * 64];
                const _Float16* arow = &u.rt.act16[wC * AP + oqC * 64];
                #pragma unroll
                for (int jj = 0; jj < 4; ++jj) {
                    f16x8 v0 = *(const f16x8*)&vrow[jj * 16];
                    f16x8 v1 = *(const f16x8*)&vrow[jj * 16 + 8];
                    f16x8 a0 = *(const f16x8*)&arow[jj * 16];
                    f16x8 a1 = *(const f16x8*)&arow[jj * 16 + 8];
                    float s = 0.f;
                    #pragma unroll
                    for (int kk = 0; kk < 4; ++kk) {
#if __has_builtin(__builtin_amdgcn_fdot2)
                        s = __builtin_amdgcn_fdot2(f16x2{v0[2 * kk], v0[2 * kk + 1]},
                                                   f16x2{a0[2 * kk], a0[2 * kk + 1]}, s, false);
                        s = __builtin_amdgcn_fdot2(f16x2{v1[2 * kk], v1[2 * kk + 1]},
                                                   f16x2{a1[2 * kk], a1[2 * kk + 1]}, s, false);
#else
                        s = fmaf((float)v0[2 * kk], (float)a0[2 * kk], s);
                        s = fmaf((float)v0[2 * kk + 1], (float)a0[2 * kk + 1], s);
                        s = fmaf((float)v1[2 * kk], (float)a1[2 * kk], s);
                        s = fmaf((float)v1[2 * kk + 1], (float)a1[2 * kk + 1], s);
#endif
                    }
                    if (it == 0) lreg4[jj] = s; else lreg4[jj] += s;
                }
            }
            // no barrier needed before next A: A touches only lreg4 + route16,
            // and route16 readers (B) are two barriers away
        }
    }

    // ---- output: out[b,h,w,o,a]; float2 stores, coalesced
    float* ob = out + (size_t)((b * 30 + h) * 30) * 256;
    #pragma unroll
    for (int w = 0; w < 4; ++w)
        if (wok[w])
            *(f32x2*)&ob[(wbase + w) * 256 + 2 * oa2] =
                f32x2{scaleA * preA[w], scaleB * preB[w]};
}

extern "C" void kernel_launch(void* const* d_in, const int* in_sizes, int n_in,
                              void* d_out, int out_size, void* d_ws, size_t ws_size,
                              hipStream_t stream)
{
    const float* x    = (const float*)d_in[0];  // [32,32,32,8,16] (raw-reshape view)
    const float* Wt   = (const float*)d_in[1];  // [16,3,3,1,256] = [144][256]
    const float* bias = (const float*)d_in[2];  // [16,16,1,1]
    float* out = (float*)d_out;                 // [32,30,30,16,16]
    _Float16* wt_h = (_Float16*)d_ws;           // [256][144] fp16 = 73,728 B

    prep_wt_kernel<<<dim3(144), 256, 0, stream>>>(Wt, wt_h);
    fused_kernel<<<dim3(960), 1024, 0, stream>>>(x, wt_h, bias, out);
}

// Round 19
// 65.641 us; speedup vs baseline: 1.1395x; 1.1395x over previous
//
#include <hip/hip_runtime.h>
#include <hip/hip_bf16.h>

typedef float    f32x2  __attribute__((ext_vector_type(2)));
typedef float    f32x4  __attribute__((ext_vector_type(4)));
typedef float    f32x16 __attribute__((ext_vector_type(16)));
typedef _Float16 f16x8  __attribute__((ext_vector_type(8)));
typedef _Float16 f16x4  __attribute__((ext_vector_type(4)));
typedef _Float16 f16x2  __attribute__((ext_vector_type(2)));

#define VP 264   // vlds co-pitch: rows 16B-aligned, 33x16B units ≡ 1 mod 8 -> b128-clean
#define XP 132   // xs plane-pitch: lane stride 66 words ≡ 2 mod 32 -> 2-way (free)
#define AP 264   // act16 pitch
#define RP 36    // route16 pitch (72B rows, b64-aligned)

// ---------------------------------------------------------------------------
// Kernel 0: W [144][256] f32 -> wt [co(256)][tap(9)][kd(16)] fp16
// ---------------------------------------------------------------------------
__global__ __launch_bounds__(256) void prep_wt_kernel(
    const float* __restrict__ W, _Float16* __restrict__ wt)
{
    const int k = blockIdx.x;      // 0..143 ; kd = k/9, tap = k%9
    const int t = threadIdx.x;     // co
    wt[t * 144 + (k % 9) * 16 + (k / 9)] = (_Float16)W[k * 256 + t];
}

// ---------------------------------------------------------------------------
// Fused kernel: block = XCD-swizzled (b,h), 1024 threads / 16 waves.
// Conv: wave = (co-tile, d-half) -> votes in vlds.
// Phase B: thread = (oa-pair, w-group-of-4): f16x2 votes, f16x4 route (r17).
// Phase A/C: 512 threads = (i, o-half, w) with w lane-fastest (conflict-free);
//            logits lreg8[8] in regs; softmax combine via shfl_xor(32).
// ---------------------------------------------------------------------------
__global__ __launch_bounds__(1024, 4) void fused_kernel(
    const float* __restrict__ x, const _Float16* __restrict__ wt,
    const float* __restrict__ bias, float* __restrict__ out)
{
    // XCD swizzle: 960 blocks = 8 XCDs x 120
    const int bid = blockIdx.x;
    const int wid = (bid & 7) * 120 + (bid >> 3);
    const int b = wid / 30, h = wid - 30 * b;
    const int t = threadIdx.x;  // 0..1023

    __shared__ alignas(16) _Float16 vlds[8 * 30 * VP];   // 126,720 B
    __shared__ alignas(16) union {
        _Float16 xs[3][36][XP];                     // 28,512 B (conv phase)
        struct {                                    // routing phase
            _Float16 route16[8 * 16 * RP];          //  9,216 B
            _Float16 act16[30 * AP];                // 15,840 B
            f32x2    s2buf[8][128];                 //  8,192 B
        } rt;
    } u;                                            // total 159,968 B

    // ---- stage x: plane-pair packed writes
    {
        const float* xb = x + (size_t)b * 131072;
        f32x4 v0[2], v1[2];
        int p0s[2], rs[2], c4s[2];
        #pragma unroll
        for (int j = 0; j < 2; ++j) {
            int q = t + j * 1024;
            bool ok = q < 1536;
            int qq = ok ? q : 0;
            int g  = qq / 24;
            p0s[j] = g * 2;
            int rem = qq - g * 24;
            rs[j] = rem >> 3; c4s[j] = rem & 7;
            if (ok) {
                v0[j] = *(const f32x4*)(xb + p0s[j] * 1024 + (h + rs[j]) * 32 + c4s[j] * 4);
                v1[j] = *(const f32x4*)(xb + (p0s[j] + 1) * 1024 + (h + rs[j]) * 32 + c4s[j] * 4);
            }
        }
        if (t < 768) {      // zero-fill cols 32..35 (plane pairs)
            int r = t / 256, rem = t - r * 256;
            int c = rem >> 6, pz = (rem & 63) * 2;
            *(f16x2*)&u.xs[r][32 + c][pz] = f16x2{(_Float16)0.f, (_Float16)0.f};
        }
        #pragma unroll
        for (int j = 0; j < 2; ++j) {
            if (t + j * 1024 < 1536) {
                #pragma unroll
                for (int c = 0; c < 4; ++c)
                    *(f16x2*)&u.xs[rs[j]][c4s[j] * 4 + c][p0s[j]] =
                        f16x2{(_Float16)v0[j][c], (_Float16)v1[j][c]};
            }
        }
    }
    __syncthreads();

    const int lane = t & 63, wv = t >> 6;   // wv 0..15
    const int l31  = lane & 31;
    const int kb   = lane >> 5;
    const int ct   = wv >> 1, dh = wv & 1;  // co-tile 0..7, d-half 0..1
    const int oaC  = ct * 32 + l31;

    // ---- conv: wave = (ct, dh): 4 d's x 9 K-steps; votes -> vlds
    {
        f16x8 bf[9];
        const _Float16* wp = wt + (size_t)oaC * 144 + kb * 8;
        #pragma unroll
        for (int s = 0; s < 9; ++s) bf[s] = *(const f16x8*)(wp + s * 16);

        #pragma unroll
        for (int dd = 0; dd < 4; ++dd) {
            f32x16 acc = {};
            #pragma unroll
            for (int s = 0; s < 9; ++s) {
                const int kh = s / 3, kw = s - 3 * (s / 3);
                const _Float16* ap = &u.xs[kh][l31 + kw][dh * 64 + dd * 16 + kb * 8];
                f16x4 lo = *(const f16x4*)(ap);
                f16x4 hi = *(const f16x4*)(ap + 4);
                f16x8 af = __builtin_shufflevector(lo, hi, 0, 1, 2, 3, 4, 5, 6, 7);
                acc = __builtin_amdgcn_mfma_f32_32x32x16_f16(af, bf[s], acc, 0, 0, 0);
            }
            const int d = dh * 4 + dd;
            #pragma unroll
            for (int r = 0; r < 16; ++r) {
                const int wr = (r & 3) + 8 * (r >> 2) + 4 * kb;
                if (wr < 30) vlds[(d * 30 + wr) * VP + oaC] = (_Float16)acc[r];
            }
        }
    }
    __syncthreads();

    // ---- routing mappings
    const int oa2 = t & 127;                // phase B: oa pair = 2*oa2, 2*oa2+1
    const int wq8 = t >> 7;                 // w-group 0..7
    const int wbase = wq8 * 4;
    const int o = oa2 >> 3;
    const float biasA = bias[2 * oa2], biasB = bias[2 * oa2 + 1];
    bool wok[4];
    #pragma unroll
    for (int w = 0; w < 4; ++w) wok[w] = (wbase + w) < 30;

    // phase A/C mapping: t < 512 -> (i = t>>6, oh = (t&63)>>5, w = t&31)
    const int iC  = t >> 6;
    const int ohC = (t & 63) >> 5;          // o-half: oo = ohC*8 .. +7
    const int wC  = t & 31;
    const bool acOK = (t < 512) && (wC < 30);

    float lreg8[8];                         // logits[iC][ohC*8+jj][wC]
    float preA[4], preB[4];
    float scaleA = 0.f, scaleB = 0.f;

    for (int it = 0; it < 3; ++it) {
        // ---- Phase A (it>0): softmax over o; shfl_xor(32) combines o-halves
        if (it > 0) {
            if (t < 512) {
                float m = lreg8[0];
                #pragma unroll
                for (int jj = 1; jj < 8; ++jj) m = fmaxf(m, lreg8[jj]);
                m = fmaxf(m, __shfl_xor(m, 32));
                float e[8], ssum = 0.f;
                #pragma unroll
                for (int jj = 0; jj < 8; ++jj) { e[jj] = __expf(lreg8[jj] - m); ssum += e[jj]; }
                ssum += __shfl_xor(ssum, 32);
                float inv = 1.f / ssum;
                if (acOK) {
                    #pragma unroll
                    for (int jj = 0; jj < 8; ++jj)
                        u.rt.route16[(iC * 16 + ohC * 8 + jj) * RP + wC] = (_Float16)(e[jj] * inv);
                }
            }
            __syncthreads();
        }

        // ---- Phase B: thread (oa2, wq8): pre over 4 w's for 2 oa's
        #pragma unroll
        for (int w = 0; w < 4; ++w) { preA[w] = biasA; preB[w] = biasB; }
        #pragma unroll
        for (int i = 0; i < 8; ++i) {
            f16x2 vv[4];
            #pragma unroll
            for (int w = 0; w < 4; ++w)
                vv[w] = wok[w] ? *(const f16x2*)&vlds[(i * 30 + wbase + w) * VP + 2 * oa2]
                               : f16x2{(_Float16)0.f, (_Float16)0.f};
            if (it == 0) {
                #pragma unroll
                for (int w = 0; w < 4; ++w) {
                    preA[w] = fmaf(0.0625f, (float)vv[w][0], preA[w]);
                    preB[w] = fmaf(0.0625f, (float)vv[w][1], preB[w]);
                }
            } else {
                f16x4 r4 = *(const f16x4*)&u.rt.route16[(i * 16 + o) * RP + wbase];
                #pragma unroll
                for (int w = 0; w < 4; ++w) {
                    float rw = (float)r4[w];
                    preA[w] = fmaf(rw, (float)vv[w][0], preA[w]);
                    preB[w] = fmaf(rw, (float)vv[w][1], preB[w]);
                }
            }
        }
        float s2A = 0.f, s2B = 0.f;
        #pragma unroll
        for (int w = 0; w < 4; ++w) {
            if (wok[w]) {
                s2A = fmaf(preA[w], preA[w], s2A);
                s2B = fmaf(preB[w], preB[w], s2B);
            }
        }
        u.rt.s2buf[wq8][oa2] = f32x2{s2A, s2B};
        __syncthreads();
        float sA = 0.f, sB = 0.f;
        #pragma unroll
        for (int k = 0; k < 8; ++k) {
            f32x2 p = u.rt.s2buf[k][oa2];
            sA += p[0]; sB += p[1];
        }
        scaleA = sA / ((1.f + sA) * sqrtf(sA + 1e-7f));
        scaleB = sB / ((1.f + sB) * sqrtf(sB + 1e-7f));

        if (it < 2) {
            #pragma unroll
            for (int w = 0; w < 4; ++w)
                if (wok[w])
                    *(f16x2*)&u.rt.act16[(wbase + w) * AP + 2 * oa2] =
                        f16x2{(_Float16)(scaleA * preA[w]), (_Float16)(scaleB * preB[w])};
            __syncthreads();
            // ---- Phase C: thread (i,oh,w) t<512: lreg8[jj] (+)= sum_a v*act
            if (acOK) {
                const _Float16* vrow = &vlds[(iC * 30 + wC) * VP + ohC * 128];
                const _Float16* arow = &u.rt.act16[wC * AP + ohC * 128];
                #pragma unroll
                for (int jj = 0; jj < 8; ++jj) {
                    f16x8 v0 = *(const f16x8*)&vrow[jj * 16];
                    f16x8 v1 = *(const f16x8*)&vrow[jj * 16 + 8];
                    f16x8 a0 = *(const f16x8*)&arow[jj * 16];
                    f16x8 a1 = *(const f16x8*)&arow[jj * 16 + 8];
                    float s = 0.f;
                    #pragma unroll
                    for (int kk = 0; kk < 4; ++kk) {
#if __has_builtin(__builtin_amdgcn_fdot2)
                        s = __builtin_amdgcn_fdot2(f16x2{v0[2 * kk], v0[2 * kk + 1]},
                                                   f16x2{a0[2 * kk], a0[2 * kk + 1]}, s, false);
                        s = __builtin_amdgcn_fdot2(f16x2{v1[2 * kk], v1[2 * kk + 1]},
                                                   f16x2{a1[2 * kk], a1[2 * kk + 1]}, s, false);
#else
                        s = fmaf((float)v0[2 * kk], (float)a0[2 * kk], s);
                        s = fmaf((float)v0[2 * kk + 1], (float)a0[2 * kk + 1], s);
                        s = fmaf((float)v1[2 * kk], (float)a1[2 * kk], s);
                        s = fmaf((float)v1[2 * kk + 1], (float)a1[2 * kk + 1], s);
#endif
                    }
                    if (it == 0) lreg8[jj] = s; else lreg8[jj] += s;
                }
            }
            // no barrier needed before next A: A touches only lreg8 + route16,
            // and route16 readers (B) are two barriers away
        }
    }

    // ---- output: out[b,h,w,o,a]; float2 stores, coalesced
    float* ob = out + (size_t)((b * 30 + h) * 30) * 256;
    #pragma unroll
    for (int w = 0; w < 4; ++w)
        if (wok[w])
            *(f32x2*)&ob[(wbase + w) * 256 + 2 * oa2] =
                f32x2{scaleA * preA[w], scaleB * preB[w]};
}

extern "C" void kernel_launch(void* const* d_in, const int* in_sizes, int n_in,
                              void* d_out, int out_size, void* d_ws, size_t ws_size,
                              hipStream_t stream)
{
    const float* x    = (const float*)d_in[0];  // [32,32,32,8,16] (raw-reshape view)
    const float* Wt   = (const float*)d_in[1];  // [16,3,3,1,256] = [144][256]
    const float* bias = (const float*)d_in[2];  // [16,16,1,1]
    float* out = (float*)d_out;                 // [32,30,30,16,16]
    _Float16* wt_h = (_Float16*)d_ws;           // [256][144] fp16 = 73,728 B

    prep_wt_kernel<<<dim3(144), 256, 0, stream>>>(Wt, wt_h);
    fused_kernel<<<dim3(960), 1024, 0, stream>>>(x, wt_h, bias, out);
}

// Round 20
// 64.365 us; speedup vs baseline: 1.1621x; 1.0198x over previous
//
#include <hip/hip_runtime.h>
#include <hip/hip_bf16.h>

typedef float    f32x2  __attribute__((ext_vector_type(2)));
typedef float    f32x4  __attribute__((ext_vector_type(4)));
typedef float    f32x16 __attribute__((ext_vector_type(16)));
typedef _Float16 f16x8  __attribute__((ext_vector_type(8)));
typedef _Float16 f16x4  __attribute__((ext_vector_type(4)));
typedef _Float16 f16x2  __attribute__((ext_vector_type(2)));

#define VP 264   // vlds co-pitch: rows 16B-aligned, 33x16B units ≡ 1 mod 8 -> b128-clean
#define XP 132   // xs plane-pitch: lane stride 66 words ≡ 2 mod 32 -> 2-way (free)
#define AP 264   // act16 pitch
#define RP 36    // route16 pitch (72B rows, b64-aligned)

// ---------------------------------------------------------------------------
// Kernel 0: W [144][256] f32 -> wt [co(256)][tap(9)][kd(16)] fp16
// ---------------------------------------------------------------------------
__global__ __launch_bounds__(256) void prep_wt_kernel(
    const float* __restrict__ W, _Float16* __restrict__ wt)
{
    const int k = blockIdx.x;      // 0..143 ; kd = k/9, tap = k%9
    const int t = threadIdx.x;     // co
    wt[t * 144 + (k % 9) * 16 + (k / 9)] = (_Float16)W[k * 256 + t];
}

// ---------------------------------------------------------------------------
// Fused kernel: block = XCD-swizzled (b,h), 1024 threads / 16 waves.
// Conv: wave = (co-tile, d-half) -> votes in vlds.
// Phase B: thread = (oa-pair, w-group-of-4): f16x2 votes, PACKED v_pk_fma_f16.
// Phase A/C: 512 threads = (i, o-half, w), w lane-fastest; lreg8 in regs.
// ---------------------------------------------------------------------------
__global__ __launch_bounds__(1024, 4) void fused_kernel(
    const float* __restrict__ x, const _Float16* __restrict__ wt,
    const float* __restrict__ bias, float* __restrict__ out)
{
    // XCD swizzle: 960 blocks = 8 XCDs x 120
    const int bid = blockIdx.x;
    const int wid = (bid & 7) * 120 + (bid >> 3);
    const int b = wid / 30, h = wid - 30 * b;
    const int t = threadIdx.x;  // 0..1023

    __shared__ alignas(16) _Float16 vlds[8 * 30 * VP];   // 126,720 B
    __shared__ alignas(16) union {
        _Float16 xs[3][36][XP];                     // 28,512 B (conv phase)
        struct {                                    // routing phase
            _Float16 route16[8 * 16 * RP];          //  9,216 B
            _Float16 act16[30 * AP];                // 15,840 B
            f32x2    s2buf[8][128];                 //  8,192 B
        } rt;
    } u;                                            // total 159,968 B

    // ---- stage x: plane-pair packed writes
    {
        const float* xb = x + (size_t)b * 131072;
        f32x4 v0[2], v1[2];
        int p0s[2], rs[2], c4s[2];
        #pragma unroll
        for (int j = 0; j < 2; ++j) {
            int q = t + j * 1024;
            bool ok = q < 1536;
            int qq = ok ? q : 0;
            int g  = qq / 24;
            p0s[j] = g * 2;
            int rem = qq - g * 24;
            rs[j] = rem >> 3; c4s[j] = rem & 7;
            if (ok) {
                v0[j] = *(const f32x4*)(xb + p0s[j] * 1024 + (h + rs[j]) * 32 + c4s[j] * 4);
                v1[j] = *(const f32x4*)(xb + (p0s[j] + 1) * 1024 + (h + rs[j]) * 32 + c4s[j] * 4);
            }
        }
        if (t < 768) {      // zero-fill cols 32..35 (plane pairs)
            int r = t / 256, rem = t - r * 256;
            int c = rem >> 6, pz = (rem & 63) * 2;
            *(f16x2*)&u.xs[r][32 + c][pz] = f16x2{(_Float16)0.f, (_Float16)0.f};
        }
        #pragma unroll
        for (int j = 0; j < 2; ++j) {
            if (t + j * 1024 < 1536) {
                #pragma unroll
                for (int c = 0; c < 4; ++c)
                    *(f16x2*)&u.xs[rs[j]][c4s[j] * 4 + c][p0s[j]] =
                        f16x2{(_Float16)v0[j][c], (_Float16)v1[j][c]};
            }
        }
    }
    __syncthreads();

    const int lane = t & 63, wv = t >> 6;   // wv 0..15
    const int l31  = lane & 31;
    const int kb   = lane >> 5;
    const int ct   = wv >> 1, dh = wv & 1;  // co-tile 0..7, d-half 0..1
    const int oaC  = ct * 32 + l31;

    // ---- conv: wave = (ct, dh): 4 d's x 9 K-steps; votes -> vlds
    {
        f16x8 bf[9];
        const _Float16* wp = wt + (size_t)oaC * 144 + kb * 8;
        #pragma unroll
        for (int s = 0; s < 9; ++s) bf[s] = *(const f16x8*)(wp + s * 16);

        #pragma unroll
        for (int dd = 0; dd < 4; ++dd) {
            f32x16 acc = {};
            #pragma unroll
            for (int s = 0; s < 9; ++s) {
                const int kh = s / 3, kw = s - 3 * (s / 3);
                const _Float16* ap = &u.xs[kh][l31 + kw][dh * 64 + dd * 16 + kb * 8];
                f16x4 lo = *(const f16x4*)(ap);
                f16x4 hi = *(const f16x4*)(ap + 4);
                f16x8 af = __builtin_shufflevector(lo, hi, 0, 1, 2, 3, 4, 5, 6, 7);
                acc = __builtin_amdgcn_mfma_f32_32x32x16_f16(af, bf[s], acc, 0, 0, 0);
            }
            const int d = dh * 4 + dd;
            #pragma unroll
            for (int r = 0; r < 16; ++r) {
                const int wr = (r & 3) + 8 * (r >> 2) + 4 * kb;
                if (wr < 30) vlds[(d * 30 + wr) * VP + oaC] = (_Float16)acc[r];
            }
        }
    }
    __syncthreads();

    // ---- routing mappings
    const int oa2 = t & 127;                // phase B: oa pair = 2*oa2, 2*oa2+1
    const int wq8 = t >> 7;                 // w-group 0..7
    const int wbase = wq8 * 4;
    const int o = oa2 >> 3;
    const f16x2 bias2 = {(_Float16)bias[2 * oa2], (_Float16)bias[2 * oa2 + 1]};
    bool wok[4];
    #pragma unroll
    for (int w = 0; w < 4; ++w) wok[w] = (wbase + w) < 30;

    // phase A/C mapping: t < 512 -> (i = t>>6, oh = (t&63)>>5, w = t&31)
    const int iC  = t >> 6;
    const int ohC = (t & 63) >> 5;          // o-half: oo = ohC*8 .. +7
    const int wC  = t & 31;
    const bool acOK = (t < 512) && (wC < 30);

    float lreg8[8];                         // logits[iC][ohC*8+jj][wC]
    float preA[4], preB[4];
    float scaleA = 0.f, scaleB = 0.f;

    for (int it = 0; it < 3; ++it) {
        // ---- Phase A (it>0): softmax over o; shfl_xor(32) combines o-halves
        if (it > 0) {
            if (t < 512) {
                float m = lreg8[0];
                #pragma unroll
                for (int jj = 1; jj < 8; ++jj) m = fmaxf(m, lreg8[jj]);
                m = fmaxf(m, __shfl_xor(m, 32));
                float e[8], ssum = 0.f;
                #pragma unroll
                for (int jj = 0; jj < 8; ++jj) { e[jj] = __expf(lreg8[jj] - m); ssum += e[jj]; }
                ssum += __shfl_xor(ssum, 32);
                float inv = 1.f / ssum;
                if (acOK) {
                    #pragma unroll
                    for (int jj = 0; jj < 8; ++jj)
                        u.rt.route16[(iC * 16 + ohC * 8 + jj) * RP + wC] = (_Float16)(e[jj] * inv);
                }
            }
            __syncthreads();
        }

        // ---- Phase B: packed fp16: pre2[w] = bias2 + sum_i route*votes (pk_fma)
        f16x2 pre2[4];
        #pragma unroll
        for (int w = 0; w < 4; ++w) pre2[w] = bias2;
        #pragma unroll
        for (int i = 0; i < 8; ++i) {
            f16x2 vv[4];
            #pragma unroll
            for (int w = 0; w < 4; ++w)
                vv[w] = wok[w] ? *(const f16x2*)&vlds[(i * 30 + wbase + w) * VP + 2 * oa2]
                               : f16x2{(_Float16)0.f, (_Float16)0.f};
            if (it == 0) {
                const f16x2 c2 = {(_Float16)0.0625f, (_Float16)0.0625f};
                #pragma unroll
                for (int w = 0; w < 4; ++w) pre2[w] = vv[w] * c2 + pre2[w];
            } else {
                f16x4 r4 = *(const f16x4*)&u.rt.route16[(i * 16 + o) * RP + wbase];
                #pragma unroll
                for (int w = 0; w < 4; ++w) {
                    f16x2 r2 = {r4[w], r4[w]};
                    pre2[w] = vv[w] * r2 + pre2[w];
                }
            }
        }
        // unpack to fp32 for squash / act / output
        #pragma unroll
        for (int w = 0; w < 4; ++w) { preA[w] = (float)pre2[w][0]; preB[w] = (float)pre2[w][1]; }
        float s2A = 0.f, s2B = 0.f;
        #pragma unroll
        for (int w = 0; w < 4; ++w) {
            if (wok[w]) {
                s2A = fmaf(preA[w], preA[w], s2A);
                s2B = fmaf(preB[w], preB[w], s2B);
            }
        }
        u.rt.s2buf[wq8][oa2] = f32x2{s2A, s2B};
        __syncthreads();
        float sA = 0.f, sB = 0.f;
        #pragma unroll
        for (int k = 0; k < 8; ++k) {
            f32x2 p = u.rt.s2buf[k][oa2];
            sA += p[0]; sB += p[1];
        }
        scaleA = sA / ((1.f + sA) * sqrtf(sA + 1e-7f));
        scaleB = sB / ((1.f + sB) * sqrtf(sB + 1e-7f));

        if (it < 2) {
            #pragma unroll
            for (int w = 0; w < 4; ++w)
                if (wok[w])
                    *(f16x2*)&u.rt.act16[(wbase + w) * AP + 2 * oa2] =
                        f16x2{(_Float16)(scaleA * preA[w]), (_Float16)(scaleB * preB[w])};
            __syncthreads();
            // ---- Phase C: thread (i,oh,w) t<512: lreg8[jj] (+)= sum_a v*act
            if (acOK) {
                const _Float16* vrow = &vlds[(iC * 30 + wC) * VP + ohC * 128];
                const _Float16* arow = &u.rt.act16[wC * AP + ohC * 128];
                #pragma unroll
                for (int jj = 0; jj < 8; ++jj) {
                    f16x8 v0 = *(const f16x8*)&vrow[jj * 16];
                    f16x8 v1 = *(const f16x8*)&vrow[jj * 16 + 8];
                    f16x8 a0 = *(const f16x8*)&arow[jj * 16];
                    f16x8 a1 = *(const f16x8*)&arow[jj * 16 + 8];
                    float s = 0.f;
                    #pragma unroll
                    for (int kk = 0; kk < 4; ++kk) {
#if __has_builtin(__builtin_amdgcn_fdot2)
                        s = __builtin_amdgcn_fdot2(f16x2{v0[2 * kk], v0[2 * kk + 1]},
                                                   f16x2{a0[2 * kk], a0[2 * kk + 1]}, s, false);
                        s = __builtin_amdgcn_fdot2(f16x2{v1[2 * kk], v1[2 * kk + 1]},
                                                   f16x2{a1[2 * kk], a1[2 * kk + 1]}, s, false);
#else
                        s = fmaf((float)v0[2 * kk], (float)a0[2 * kk], s);
                        s = fmaf((float)v0[2 * kk + 1], (float)a0[2 * kk + 1], s);
                        s = fmaf((float)v1[2 * kk], (float)a1[2 * kk], s);
                        s = fmaf((float)v1[2 * kk + 1], (float)a1[2 * kk + 1], s);
#endif
                    }
                    if (it == 0) lreg8[jj] = s; else lreg8[jj] += s;
                }
            }
            // no barrier needed before next A: A touches only lreg8 + route16,
            // and route16 readers (B) are two barriers away
        }
    }

    // ---- output: out[b,h,w,o,a]; float2 stores, coalesced
    float* ob = out + (size_t)((b * 30 + h) * 30) * 256;
    #pragma unroll
    for (int w = 0; w < 4; ++w)
        if (wok[w])
            *(f32x2*)&ob[(wbase + w) * 256 + 2 * oa2] =
                f32x2{scaleA * preA[w], scaleB * preB[w]};
}

extern "C" void kernel_launch(void* const* d_in, const int* in_sizes, int n_in,
                              void* d_out, int out_size, void* d_ws, size_t ws_size,
                              hipStream_t stream)
{
    const float* x    = (const float*)d_in[0];  // [32,32,32,8,16] (raw-reshape view)
    const float* Wt   = (const float*)d_in[1];  // [16,3,3,1,256] = [144][256]
    const float* bias = (const float*)d_in[2];  // [16,16,1,1]
    float* out = (float*)d_out;                 // [32,30,30,16,16]
    _Float16* wt_h = (_Float16*)d_ws;           // [256][144] fp16 = 73,728 B

    prep_wt_kernel<<<dim3(144), 256, 0, stream>>>(Wt, wt_h);
    fused_kernel<<<dim3(960), 1024, 0, stream>>>(x, wt_h, bias, out);
}